// Round 1
// baseline (1720.213 us; speedup 1.0000x reference)
//
#include <hip/hip_runtime.h>
#include <math.h>

// Problem shape (fixed by reference):
//   x: [64,1024,256] f32 -> 65536 tokens x 256
//   codebook: [4096,256] f32
// Outputs concatenated in d_out (f32): ids(65536, as float) | emb(65536*256) | loss(1)

#define TOKENS 65536
#define DIM 256
#define KCB 4096

#define BM 128   // tokens per block
#define BN 128   // codes per tile
#define DC 32    // d-chunk staged in LDS

// ---------------- kernel 1: normalize codebook rows ----------------
__global__ void norm_cb_kernel(const float* __restrict__ cb, float* __restrict__ cbn) {
    int row  = blockIdx.x * 4 + (threadIdx.x >> 6);
    int lane = threadIdx.x & 63;
    float4 v = *(const float4*)(cb + (size_t)row * DIM + lane * 4);
    float ss = v.x * v.x + v.y * v.y + v.z * v.z + v.w * v.w;
#pragma unroll
    for (int off = 32; off; off >>= 1) ss += __shfl_xor(ss, off);
    float scale = 1.0f / fmaxf(sqrtf(ss), 1e-12f);
    float4 o = {v.x * scale, v.y * scale, v.z * scale, v.w * scale};
    *(float4*)(cbn + (size_t)row * DIM + lane * 4) = o;
}

// ---------------- kernel 1b: per-token 1/max(||x||,eps) ----------------
__global__ void x_norm_kernel(const float* __restrict__ x, float* __restrict__ invnx) {
    int row  = blockIdx.x * 4 + (threadIdx.x >> 6);
    int lane = threadIdx.x & 63;
    float4 v = *(const float4*)(x + (size_t)row * DIM + lane * 4);
    float ss = v.x * v.x + v.y * v.y + v.z * v.z + v.w * v.w;
#pragma unroll
    for (int off = 32; off; off >>= 1) ss += __shfl_xor(ss, off);
    if (lane == 0) invnx[row] = 1.0f / fmaxf(sqrtf(ss), 1e-12f);
}

// ---------------- kernel 2: fp32 GEMM (x @ cbn^T) + fused argmin(1-s) ----------------
// 256 threads = 16x16 grid, 8x8 micro-tile each. A,B staged d-major in LDS with
// XOR slot swizzle pi(s)=s^(s>>3) -> conflict-free transpose writes AND frag reads.
__global__ __launch_bounds__(256) void argmin_kernel(
    const float* __restrict__ x, const float* __restrict__ cbn,
    const float* __restrict__ invnx,
    float* __restrict__ out_ids_f, int* __restrict__ out_ids_i) {
    __shared__ float As[DC * BM];
    __shared__ float Bs[DC * BN];

    const int tid = threadIdx.x;
    const int ty = tid >> 4;        // 0..15 -> tokens ty*8..ty*8+7
    const int tx = tid & 15;        // 0..15 -> codes  tx*8..tx*8+7
    const int tb = blockIdx.x * BM; // token base

    float inv[8];
#pragma unroll
    for (int i = 0; i < 8; i++) inv[i] = invnx[tb + ty * 8 + i];

    float bestd[8];
    int   besti[8];
#pragma unroll
    for (int i = 0; i < 8; i++) { bestd[i] = 3.0e38f; besti[i] = 0; }

    // staging: 2 threads per row, 16 floats each (4 x float4)
    const int sr = tid >> 1;   // row in tile (token or code), 0..127
    const int sh = tid & 1;    // half of the 32-wide d-chunk
    const int wslot = sr >> 2;
    const int wcol = (((wslot ^ (wslot >> 3)) & 31) << 2) + (sr & 3);

    // fragment read columns (swizzled)
    const int as0 = ty * 2,     as1 = ty * 2 + 1;
    const int bs0 = tx * 2,     bs1 = tx * 2 + 1;
    const int ac0 = ((as0 ^ (as0 >> 3)) & 31) << 2;
    const int ac1 = ((as1 ^ (as1 >> 3)) & 31) << 2;
    const int bc0 = ((bs0 ^ (bs0 >> 3)) & 31) << 2;
    const int bc1 = ((bs1 ^ (bs1 >> 3)) & 31) << 2;

    for (int ct = 0; ct < KCB / BN; ++ct) {
        float acc[8][8];
#pragma unroll
        for (int i = 0; i < 8; i++)
#pragma unroll
            for (int j = 0; j < 8; j++) acc[i][j] = 0.0f;

        for (int dcb = 0; dcb < DIM / DC; ++dcb) {
            const int dbase = dcb * DC;
            const float* xa = x   + (size_t)(tb + sr) * DIM + dbase + sh * 16;
            const float* bb = cbn + (size_t)(ct * BN + sr) * DIM + dbase + sh * 16;
#pragma unroll
            for (int q = 0; q < 4; q++) {
                float4 av = *(const float4*)(xa + q * 4);
                float4 bv = *(const float4*)(bb + q * 4);
                int d0 = sh * 16 + q * 4;
                As[(d0 + 0) * BM + wcol] = av.x;
                As[(d0 + 1) * BM + wcol] = av.y;
                As[(d0 + 2) * BM + wcol] = av.z;
                As[(d0 + 3) * BM + wcol] = av.w;
                Bs[(d0 + 0) * BN + wcol] = bv.x;
                Bs[(d0 + 1) * BN + wcol] = bv.y;
                Bs[(d0 + 2) * BN + wcol] = bv.z;
                Bs[(d0 + 3) * BN + wcol] = bv.w;
            }
            __syncthreads();
#pragma unroll
            for (int d = 0; d < DC; ++d) {
                float4 a0 = *(const float4*)&As[d * BM + ac0];
                float4 a1 = *(const float4*)&As[d * BM + ac1];
                float4 b0 = *(const float4*)&Bs[d * BN + bc0];
                float4 b1 = *(const float4*)&Bs[d * BN + bc1];
                float a[8] = {a0.x, a0.y, a0.z, a0.w, a1.x, a1.y, a1.z, a1.w};
                float b[8] = {b0.x, b0.y, b0.z, b0.w, b1.x, b1.y, b1.z, b1.w};
#pragma unroll
                for (int i = 0; i < 8; i++)
#pragma unroll
                    for (int j = 0; j < 8; j++)
                        acc[i][j] = fmaf(a[i], b[j], acc[i][j]);
            }
            __syncthreads();
        }
        // fold tile into running argmin of d = 1 - s (reference tie semantics)
#pragma unroll
        for (int i = 0; i < 8; i++) {
#pragma unroll
            for (int j = 0; j < 8; j++) {
                float s = acc[i][j] * inv[i];
                float dd = 1.0f - s;
                int id = ct * BN + tx * 8 + j;
                if (dd < bestd[i]) { bestd[i] = dd; besti[i] = id; }
            }
        }
    }

    // reduce across the 16 tx lanes sharing each token row (first-min tie-break on id)
#pragma unroll
    for (int i = 0; i < 8; i++) {
        float bd = bestd[i];
        int   bi = besti[i];
#pragma unroll
        for (int off = 1; off < 16; off <<= 1) {
            float od = __shfl_xor(bd, off);
            int   oi = __shfl_xor(bi, off);
            if (od < bd || (od == bd && oi < bi)) { bd = od; bi = oi; }
        }
        if (tx == 0) {
            int t = tb + ty * 8 + i;
            out_ids_f[t] = (float)bi;
            out_ids_i[t] = bi;
        }
    }
}

// ---------------- kernel 3: gather + weighted emb + per-block loss partial ----------------
__global__ void epilogue_kernel(const float* __restrict__ x, const float* __restrict__ cbn,
                                const float* __restrict__ invnx, const int* __restrict__ ids,
                                float* __restrict__ emb, float* __restrict__ partials) {
    int w    = threadIdx.x >> 6; // wave within block (1 token per wave)
    int lane = threadIdx.x & 63;
    int t    = blockIdx.x * 4 + w;
    int id   = ids[t];
    float4 c4 = *(const float4*)(cbn + (size_t)id * DIM + lane * 4);
    float4 x4 = *(const float4*)(x + (size_t)t * DIM + lane * 4);
    float dxc = c4.x * x4.x + c4.y * x4.y + c4.z * x4.z + c4.w * x4.w;
    float ssc = c4.x * c4.x + c4.y * c4.y + c4.z * c4.z + c4.w * c4.w;
#pragma unroll
    for (int off = 32; off; off >>= 1) {
        dxc += __shfl_xor(dxc, off);
        ssc += __shfl_xor(ssc, off);
    }
    float cosk = fmaxf(dxc, 1e-6f); // raw-x cosine weight, clamped
    float4 o = {cosk * c4.x, cosk * c4.y, cosk * c4.z, cosk * c4.w};
    *(float4*)(emb + (size_t)t * DIM + lane * 4) = o;

    // loss term: 1 - dot(x_n, c_k / max(||c_k||,eps))
    float invnc = 1.0f / fmaxf(sqrtf(ssc), 1e-12f);
    float term = 1.0f - dxc * invnx[t] * invnc;

    __shared__ float sterm[4];
    if (lane == 0) sterm[w] = term;
    __syncthreads();
    if (threadIdx.x == 0)
        partials[blockIdx.x] = sterm[0] + sterm[1] + sterm[2] + sterm[3];
}

// ---------------- kernel 4: deterministic loss finalize ----------------
__global__ void finalize_kernel(const float* __restrict__ partials, float* __restrict__ loss) {
    __shared__ float buf[256];
    float s = 0.0f;
    for (int i = threadIdx.x; i < TOKENS / 4; i += 256) s += partials[i];
    buf[threadIdx.x] = s;
    __syncthreads();
    for (int st = 128; st; st >>= 1) {
        if (threadIdx.x < st) buf[threadIdx.x] += buf[threadIdx.x + st];
        __syncthreads();
    }
    // loss = codebook_term + BETA*commit_term = 1.25 * mean(1 - cos)
    if (threadIdx.x == 0) loss[0] = buf[0] * (1.25f / (float)TOKENS);
}

extern "C" void kernel_launch(void* const* d_in, const int* in_sizes, int n_in,
                              void* d_out, int out_size, void* d_ws, size_t ws_size,
                              hipStream_t stream) {
    const float* x  = (const float*)d_in[0];
    const float* cb = (const float*)d_in[1];

    float* out    = (float*)d_out;
    float* ids_f  = out;                              // 65536 floats
    float* emb    = out + TOKENS;                     // 65536*256 floats
    float* loss   = out + TOKENS + (size_t)TOKENS * DIM; // 1 float

    float* ws       = (float*)d_ws;
    float* cbn      = ws;                              // 4096*256
    float* invnx    = ws + (size_t)KCB * DIM;          // 65536
    int*   ids_i    = (int*)(ws + (size_t)KCB * DIM + TOKENS); // 65536 ints
    float* partials = ws + (size_t)KCB * DIM + 2 * (size_t)TOKENS; // 16384

    norm_cb_kernel<<<KCB / 4, 256, 0, stream>>>(cb, cbn);
    x_norm_kernel<<<TOKENS / 4, 256, 0, stream>>>(x, invnx);
    argmin_kernel<<<TOKENS / BM, 256, 0, stream>>>(x, cbn, invnx, ids_f, ids_i);
    epilogue_kernel<<<TOKENS / 4, 256, 0, stream>>>(x, cbn, invnx, ids_i, emb, partials);
    finalize_kernel<<<1, 256, 0, stream>>>(partials, loss);
}

// Round 2
// 1597.889 us; speedup vs baseline: 1.0766x; 1.0766x over previous
//
#include <hip/hip_runtime.h>
#include <math.h>

// Problem shape (fixed by reference):
//   x: [64,1024,256] f32 -> 65536 tokens x 256
//   codebook: [4096,256] f32
// Outputs concatenated in d_out (f32): ids(65536, as float) | emb(65536*256) | loss(1)

#define TOKENS 65536
#define DIM 256
#define KCB 4096

#define BM 128   // tokens per block
#define BN 128   // codes per tile
#define DC 32    // d-chunk staged in LDS
#define KSPLIT 4 // blocks sharing one token stripe (each scans KCB/KSPLIT codes)
#define CTP (KCB / BN / KSPLIT) // code tiles per block = 8

// ---------------- kernel 1: normalize codebook rows ----------------
__global__ void norm_cb_kernel(const float* __restrict__ cb, float* __restrict__ cbn) {
    int row  = blockIdx.x * 4 + (threadIdx.x >> 6);
    int lane = threadIdx.x & 63;
    float4 v = *(const float4*)(cb + (size_t)row * DIM + lane * 4);
    float ss = v.x * v.x + v.y * v.y + v.z * v.z + v.w * v.w;
#pragma unroll
    for (int off = 32; off; off >>= 1) ss += __shfl_xor(ss, off);
    float scale = 1.0f / fmaxf(sqrtf(ss), 1e-12f);
    float4 o = {v.x * scale, v.y * scale, v.z * scale, v.w * scale};
    *(float4*)(cbn + (size_t)row * DIM + lane * 4) = o;
}

// ---------------- kernel 1b: per-token 1/max(||x||,eps) ----------------
__global__ void x_norm_kernel(const float* __restrict__ x, float* __restrict__ invnx) {
    int row  = blockIdx.x * 4 + (threadIdx.x >> 6);
    int lane = threadIdx.x & 63;
    float4 v = *(const float4*)(x + (size_t)row * DIM + lane * 4);
    float ss = v.x * v.x + v.y * v.y + v.z * v.z + v.w * v.w;
#pragma unroll
    for (int off = 32; off; off >>= 1) ss += __shfl_xor(ss, off);
    if (lane == 0) invnx[row] = 1.0f / fmaxf(sqrtf(ss), 1e-12f);
}

// ---------------- kernel 2: fp32 GEMM (x @ cbn^T) + fused argmin(1-s) ----------------
// Split-K: blockIdx.y selects a 1024-code range; per-token candidates merged in epilogue.
// 256 threads = 16x16 grid, 8x8 micro-tile each. A,B staged d-major in LDS with
// XOR slot swizzle pi(s)=s^(s>>3) -> conflict-free transpose writes AND frag reads.
__global__ __launch_bounds__(256) void argmin_kernel(
    const float* __restrict__ x, const float* __restrict__ cbn,
    const float* __restrict__ invnx,
    float* __restrict__ cand_d, int* __restrict__ cand_i) {
    __shared__ float As[DC * BM];
    __shared__ float Bs[DC * BN];

    const int tid = threadIdx.x;
    const int ty = tid >> 4;        // 0..15 -> tokens ty*8..ty*8+7
    const int tx = tid & 15;        // 0..15 -> codes  tx*8..tx*8+7
    const int tb = blockIdx.x * BM; // token base
    const int ky = blockIdx.y;      // k-split index
    const int ct0 = ky * CTP;

    float inv[8];
#pragma unroll
    for (int i = 0; i < 8; i++) inv[i] = invnx[tb + ty * 8 + i];

    float bestd[8];
    int   besti[8];
#pragma unroll
    for (int i = 0; i < 8; i++) { bestd[i] = 3.0e38f; besti[i] = 0; }

    // staging: 2 threads per row, 16 floats each (4 x float4)
    const int sr = tid >> 1;   // row in tile (token or code), 0..127
    const int sh = tid & 1;    // half of the 32-wide d-chunk
    const int wslot = sr >> 2;
    const int wcol = (((wslot ^ (wslot >> 3)) & 31) << 2) + (sr & 3);

    // fragment read columns (swizzled)
    const int as0 = ty * 2,     as1 = ty * 2 + 1;
    const int bs0 = tx * 2,     bs1 = tx * 2 + 1;
    const int ac0 = ((as0 ^ (as0 >> 3)) & 31) << 2;
    const int ac1 = ((as1 ^ (as1 >> 3)) & 31) << 2;
    const int bc0 = ((bs0 ^ (bs0 >> 3)) & 31) << 2;
    const int bc1 = ((bs1 ^ (bs1 >> 3)) & 31) << 2;

    const float* xrow = x + (size_t)(tb + sr) * DIM + sh * 16;

    for (int ct = ct0; ct < ct0 + CTP; ++ct) {
        float acc[8][8];
#pragma unroll
        for (int i = 0; i < 8; i++)
#pragma unroll
            for (int j = 0; j < 8; j++) acc[i][j] = 0.0f;

        const float* xp = xrow;
        const float* bp = cbn + (size_t)(ct * BN + sr) * DIM + sh * 16;

        for (int dcb = 0; dcb < DIM / DC; ++dcb, xp += DC, bp += DC) {
#pragma unroll
            for (int q = 0; q < 4; q++) {
                float4 av = *(const float4*)(xp + q * 4);
                float4 bv = *(const float4*)(bp + q * 4);
                int d0 = sh * 16 + q * 4;
                As[(d0 + 0) * BM + wcol] = av.x;
                As[(d0 + 1) * BM + wcol] = av.y;
                As[(d0 + 2) * BM + wcol] = av.z;
                As[(d0 + 3) * BM + wcol] = av.w;
                Bs[(d0 + 0) * BN + wcol] = bv.x;
                Bs[(d0 + 1) * BN + wcol] = bv.y;
                Bs[(d0 + 2) * BN + wcol] = bv.z;
                Bs[(d0 + 3) * BN + wcol] = bv.w;
            }
            __syncthreads();
#pragma unroll
            for (int d = 0; d < DC; ++d) {
                float4 a0 = *(const float4*)&As[d * BM + ac0];
                float4 a1 = *(const float4*)&As[d * BM + ac1];
                float4 b0 = *(const float4*)&Bs[d * BN + bc0];
                float4 b1 = *(const float4*)&Bs[d * BN + bc1];
                float a[8] = {a0.x, a0.y, a0.z, a0.w, a1.x, a1.y, a1.z, a1.w};
                float b[8] = {b0.x, b0.y, b0.z, b0.w, b1.x, b1.y, b1.z, b1.w};
#pragma unroll
                for (int i = 0; i < 8; i++)
#pragma unroll
                    for (int j = 0; j < 8; j++)
                        acc[i][j] = fmaf(a[i], b[j], acc[i][j]);
            }
            __syncthreads();
        }
        // fold tile into running argmin of d = 1 - s (reference tie semantics)
#pragma unroll
        for (int i = 0; i < 8; i++) {
#pragma unroll
            for (int j = 0; j < 8; j++) {
                float s = acc[i][j] * inv[i];
                float dd = 1.0f - s;
                int id = ct * BN + tx * 8 + j;
                if (dd < bestd[i]) { bestd[i] = dd; besti[i] = id; }
            }
        }
    }

    // reduce across the 16 tx lanes sharing each token row (first-min tie-break on id)
#pragma unroll
    for (int i = 0; i < 8; i++) {
        float bd = bestd[i];
        int   bi = besti[i];
#pragma unroll
        for (int off = 1; off < 16; off <<= 1) {
            float od = __shfl_xor(bd, off);
            int   oi = __shfl_xor(bi, off);
            if (od < bd || (od == bd && oi < bi)) { bd = od; bi = oi; }
        }
        if (tx == 0) {
            int t = tb + ty * 8 + i;
            cand_d[ky * TOKENS + t] = bd;
            cand_i[ky * TOKENS + t] = bi;
        }
    }
}

// ---------------- kernel 3: merge candidates + gather + weighted emb + loss partial ----------------
__global__ void epilogue_kernel(const float* __restrict__ x, const float* __restrict__ cbn,
                                const float* __restrict__ invnx,
                                const float* __restrict__ cand_d, const int* __restrict__ cand_i,
                                float* __restrict__ ids_f,
                                float* __restrict__ emb, float* __restrict__ partials) {
    int w    = threadIdx.x >> 6; // wave within block (1 token per wave)
    int lane = threadIdx.x & 63;
    int t    = blockIdx.x * 4 + w;

    // merge the KSPLIT candidates (ids monotone in k -> strict < keeps first occurrence)
    float bd = cand_d[t];
    int   id = cand_i[t];
#pragma unroll
    for (int k = 1; k < KSPLIT; k++) {
        float od = cand_d[k * TOKENS + t];
        int   oi = cand_i[k * TOKENS + t];
        if (od < bd) { bd = od; id = oi; }
    }
    if (lane == 0) ids_f[t] = (float)id;

    float4 c4 = *(const float4*)(cbn + (size_t)id * DIM + lane * 4);
    float4 x4 = *(const float4*)(x + (size_t)t * DIM + lane * 4);
    float dxc = c4.x * x4.x + c4.y * x4.y + c4.z * x4.z + c4.w * x4.w;
    float ssc = c4.x * c4.x + c4.y * c4.y + c4.z * c4.z + c4.w * c4.w;
#pragma unroll
    for (int off = 32; off; off >>= 1) {
        dxc += __shfl_xor(dxc, off);
        ssc += __shfl_xor(ssc, off);
    }
    float cosk = fmaxf(dxc, 1e-6f); // raw-x cosine weight, clamped
    float4 o = {cosk * c4.x, cosk * c4.y, cosk * c4.z, cosk * c4.w};
    *(float4*)(emb + (size_t)t * DIM + lane * 4) = o;

    // loss term: 1 - dot(x_n, c_k / max(||c_k||,eps))
    float invnc = 1.0f / fmaxf(sqrtf(ssc), 1e-12f);
    float term = 1.0f - dxc * invnx[t] * invnc;

    __shared__ float sterm[4];
    if (lane == 0) sterm[w] = term;
    __syncthreads();
    if (threadIdx.x == 0)
        partials[blockIdx.x] = sterm[0] + sterm[1] + sterm[2] + sterm[3];
}

// ---------------- kernel 4: deterministic loss finalize ----------------
__global__ void finalize_kernel(const float* __restrict__ partials, float* __restrict__ loss) {
    __shared__ float buf[256];
    float s = 0.0f;
    for (int i = threadIdx.x; i < TOKENS / 4; i += 256) s += partials[i];
    buf[threadIdx.x] = s;
    __syncthreads();
    for (int st = 128; st; st >>= 1) {
        if (threadIdx.x < st) buf[threadIdx.x] += buf[threadIdx.x + st];
        __syncthreads();
    }
    // loss = codebook_term + BETA*commit_term = 1.25 * mean(1 - cos)
    if (threadIdx.x == 0) loss[0] = buf[0] * (1.25f / (float)TOKENS);
}

extern "C" void kernel_launch(void* const* d_in, const int* in_sizes, int n_in,
                              void* d_out, int out_size, void* d_ws, size_t ws_size,
                              hipStream_t stream) {
    const float* x  = (const float*)d_in[0];
    const float* cb = (const float*)d_in[1];

    float* out    = (float*)d_out;
    float* ids_f  = out;                              // 65536 floats
    float* emb    = out + TOKENS;                     // 65536*256 floats
    float* loss   = out + TOKENS + (size_t)TOKENS * DIM; // 1 float

    float* ws       = (float*)d_ws;
    float* cbn      = ws;                                       // 4096*256
    float* invnx    = cbn + (size_t)KCB * DIM;                  // 65536
    float* cand_d   = invnx + TOKENS;                           // KSPLIT*65536
    int*   cand_i   = (int*)(cand_d + (size_t)KSPLIT * TOKENS); // KSPLIT*65536
    float* partials = (float*)(cand_i + (size_t)KSPLIT * TOKENS); // 16384

    norm_cb_kernel<<<KCB / 4, 256, 0, stream>>>(cb, cbn);
    x_norm_kernel<<<TOKENS / 4, 256, 0, stream>>>(x, invnx);
    dim3 grid(TOKENS / BM, KSPLIT);
    argmin_kernel<<<grid, 256, 0, stream>>>(x, cbn, invnx, cand_d, cand_i);
    epilogue_kernel<<<TOKENS / 4, 256, 0, stream>>>(x, cbn, invnx, cand_d, cand_i,
                                                    ids_f, emb, partials);
    finalize_kernel<<<1, 256, 0, stream>>>(partials, loss);
}